// Round 1
// baseline (5034.246 us; speedup 1.0000x reference)
//
#include <hip/hip_runtime.h>
#include <math.h>

#define BSZ 4
#define NN 1024
#define BH 8
#define DD 64
#define MM 2048
#define KRET 16
#define CC 64
#define NEGV -1000000000.0f
#define EPSV 1e-8f
#define SMAXV 4.0f
#define BUDGETV 512.0f

// ws layout (float-element offsets)
#define WS_NOV  0         // [32][1024] novelty (transposed to [s*8+b][n])
#define WS_CI   32768     // int [32][64] candidate indices
#define WS_CW   34816     // [32][64] cand_weight
#define WS_CKN  36864     // [32][64][64] unit-normalized cand_K
#define WS_CV   167936    // [32][64][64] cand_V
#define WS_MAXC 299008    // [32][64] slot-softmax row max
#define WS_SUMC 301056    // [32][64] slot-softmax row sumexp
#define WS_TOTS 303104    // [32] new_S totals (memset to 0 each call)

// ---------------------------------------------------------------------------
// Kernel 1: scores = q.K^T with top-16 + softmax + P.V, sim = q_nov.K^T max,
// novelty output. One block = (s,b) x 16 rows of n. LDS-staged K tiles (128).
// ---------------------------------------------------------------------------
__global__ __launch_bounds__(256)
void k1_read(const float* __restrict__ q, const float* __restrict__ qn,
             const float* __restrict__ surprise, const float* __restrict__ wnov,
             const float* __restrict__ emK, const float* __restrict__ emV,
             const float* __restrict__ emS, float* __restrict__ out,
             float* __restrict__ ws)
{
    const int sb = blockIdx.x;            // 0..31  (s*8+b) -> XCD locality
    const int s = sb >> 3, b = sb & 7;
    const int n0 = blockIdx.y << 4;       // n-tile of 16
    const int t = threadIdx.x;
    const int ir = t >> 4;                // row in tile 0..15
    const int c  = t & 15;                // sub-lane in row 0..15

    __shared__ float qs[16][68];
    __shared__ float qsn[16][68];
    __shared__ float Kt[128][68];
    __shared__ float Sm[128];
    __shared__ float win_e[16][16];
    __shared__ int   win_i[16][16];

    {
        const size_t qb = (((size_t)s*NN + n0 + ir)*BH + b)*DD + (c << 2);
        *(float4*)&qs[ir][c << 2]  = *(const float4*)&q[qb];
        *(float4*)&qsn[ir][c << 2] = *(const float4*)&qn[qb];
    }

    float tv[16]; int ti[16];
    #pragma unroll
    for (int i = 0; i < 16; ++i) { tv[i] = -3.0e38f; ti[i] = 0; }
    float minv = -3.0e38f; int minp = 0;
    float nsim = -3.0e38f;

    const float* Kb = emK + (size_t)sb*MM*DD;
    const float* Sb = emS + (size_t)sb*MM;

    #pragma unroll 1
    for (int mt = 0; mt < MM/128; ++mt) {
        __syncthreads();   // protect Kt from previous-iter readers
        #pragma unroll
        for (int k = 0; k < 8; ++k) {
            const int fid = t + (k << 8);
            const int row = fid >> 4;
            const int col = (fid & 15) << 2;
            *(float4*)&Kt[row][col] =
                *(const float4*)&Kb[((size_t)(mt*128 + row))*DD + col];
        }
        if (t < 128) Sm[t] = Sb[mt*128 + t];
        __syncthreads();

        float acc[8], accn[8];
        #pragma unroll
        for (int j = 0; j < 8; ++j) { acc[j] = 0.f; accn[j] = 0.f; }
        #pragma unroll
        for (int ch = 0; ch < 16; ++ch) {
            const float4 q4 = *(const float4*)&qs[ir][ch << 2];
            const float4 n4 = *(const float4*)&qsn[ir][ch << 2];
            #pragma unroll
            for (int j = 0; j < 8; ++j) {
                const float4 k4 = *(const float4*)&Kt[c + (j << 4)][ch << 2];
                acc[j]  += q4.x*k4.x + q4.y*k4.y + q4.z*k4.z + q4.w*k4.w;
                accn[j] += n4.x*k4.x + n4.y*k4.y + n4.z*k4.z + n4.w*k4.w;
            }
        }
        #pragma unroll
        for (int j = 0; j < 8; ++j) {
            const int ml = c + (j << 4);
            const bool act = Sm[ml] > 0.f;
            const float sq = act ? acc[j] : NEGV;
            nsim = fmaxf(nsim, act ? accn[j] : -1.0f);
            if (sq > minv) {
                const int gm = mt*128 + ml;
                #pragma unroll
                for (int i = 0; i < 16; ++i)
                    if (i == minp) { tv[i] = sq; ti[i] = gm; }
                minv = tv[0]; minp = 0;
                #pragma unroll
                for (int i = 1; i < 16; ++i)
                    if (tv[i] < minv) { minv = tv[i]; minp = i; }
            }
        }
    }

    // ---- merge per-row top-16 across the row's 16 lanes ----
    float m0 = 0.f;
    #pragma unroll 1
    for (int k = 0; k < 16; ++k) {
        float lv = tv[0]; int ls = 0;
        #pragma unroll
        for (int i = 1; i < 16; ++i) if (tv[i] > lv) { lv = tv[i]; ls = i; }
        int key = (c << 4) | ls;
        #pragma unroll
        for (int off = 8; off >= 1; off >>= 1) {
            const float ov = __shfl_xor(lv, off, 16);
            const int   ok = __shfl_xor(key, off, 16);
            if (ov > lv || (ov == lv && ok < key)) { lv = ov; key = ok; }
        }
        if (k == 0) m0 = lv;
        if ((key >> 4) == c) {
            const int sl = key & 15;
            int wi = 0;
            #pragma unroll
            for (int i = 0; i < 16; ++i) if (i == sl) wi = ti[i];
            win_e[ir][k] = __expf(lv - m0);
            win_i[ir][k] = wi;
            #pragma unroll
            for (int i = 0; i < 16; ++i) if (i == sl) tv[i] = -3.0e38f;
        }
    }
    __syncthreads();

    // ---- softmax over the 16 kept entries + P.V gather ----
    const float e_c = win_e[ir][c];
    const int   i_c = win_i[ir][c];
    float den = e_c;
    #pragma unroll
    for (int off = 8; off >= 1; off >>= 1) den += __shfl_xor(den, off, 16);
    const float wgt = e_c / den;

    float4 o4 = make_float4(0.f, 0.f, 0.f, 0.f);
    const float* Vb = emV + (size_t)sb*MM*DD;
    for (int k = 0; k < 16; ++k) {
        const float wk = __shfl(wgt, k, 16);
        const int   ik = __shfl(i_c, k, 16);
        const float4 v4 = *(const float4*)&Vb[(size_t)ik*DD + (c << 2)];
        o4.x += wk*v4.x; o4.y += wk*v4.y; o4.z += wk*v4.z; o4.w += wk*v4.w;
    }
    *(float4*)&out[(((size_t)s*NN + n0 + ir)*BH + b)*DD + (c << 2)] = o4;

    // ---- novelty ----
    #pragma unroll
    for (int off = 8; off >= 1; off >>= 1)
        nsim = fmaxf(nsim, __shfl_xor(nsim, off, 16));
    if (c == 0) {
        const int ni = ((s*NN + n0 + ir)*BH) + b;
        const float w = wnov[ni], su = surprise[ni];
        ws[WS_NOV + sb*NN + n0 + ir] = w*su + (1.f - w)*(1.f - fmaxf(nsim, 0.f));
    }
}

// ---------------------------------------------------------------------------
// Kernel 2: per (s,b) top-64 of novelty over N=1024 + cand_weight
// ---------------------------------------------------------------------------
__global__ __launch_bounds__(256)
void k2_topc(float* __restrict__ ws)
{
    const int sb = blockIdx.x;
    const int t = threadIdx.x;
    __shared__ float nv[NN];
    __shared__ float rv[4]; __shared__ int ri[4];
    __shared__ float kvv[CC]; __shared__ int kii[CC];

    #pragma unroll
    for (int k = 0; k < 4; ++k) nv[t + (k << 8)] = ws[WS_NOV + sb*NN + t + (k << 8)];
    __syncthreads();
    const int lane = t & 63, w = t >> 6;

    for (int k = 0; k < CC; ++k) {
        float lv = -3.0e38f; int li = 0;
        #pragma unroll
        for (int j = 0; j < 4; ++j) {
            const int idx = t + (j << 8);
            const float v = nv[idx];
            if (v > lv) { lv = v; li = idx; }
        }
        #pragma unroll
        for (int off = 32; off >= 1; off >>= 1) {
            const float ov = __shfl_xor(lv, off, 64);
            const int   oi = __shfl_xor(li, off, 64);
            if (ov > lv || (ov == lv && oi < li)) { lv = ov; li = oi; }
        }
        if (lane == 0) { rv[w] = lv; ri[w] = li; }
        __syncthreads();
        if (t == 0) {
            float bv2 = rv[0]; int bi = ri[0];
            for (int j = 1; j < 4; ++j)
                if (rv[j] > bv2 || (rv[j] == bv2 && ri[j] < bi)) { bv2 = rv[j]; bi = ri[j]; }
            kvv[k] = bv2; kii[k] = bi;
            nv[bi] = -3.0e38f;
        }
        __syncthreads();
    }

    if (t < CC) {
        const float v = kvv[t];
        float sum = v;
        #pragma unroll
        for (int off = 32; off >= 1; off >>= 1) sum += __shfl_xor(sum, off, 64);
        ((int*)ws)[WS_CI + sb*CC + t] = kii[t];
        ws[WS_CW + sb*CC + t] = v / (sum + EPSV);
    }
}

// ---------------------------------------------------------------------------
// Kernel 3a: gather cand_K/cand_V, unit-normalize cand_K
// ---------------------------------------------------------------------------
__global__ __launch_bounds__(256)
void k3a_gather(const float* __restrict__ qn, const float* __restrict__ vn,
                float* __restrict__ ws)
{
    const int sb = blockIdx.x; const int s = sb >> 3, b = sb & 7;
    const int t = threadIdx.x;
    const int cc = t >> 2, qd = t & 3;
    const int idx = ((const int*)ws)[WS_CI + sb*CC + cc];
    const size_t base = (((size_t)s*NN + idx)*BH + b)*DD + qd*16;

    float4 a[4]; float ss = 0.f;
    #pragma unroll
    for (int k = 0; k < 4; ++k) {
        a[k] = *(const float4*)&qn[base + (k << 2)];
        ss += a[k].x*a[k].x + a[k].y*a[k].y + a[k].z*a[k].z + a[k].w*a[k].w;
    }
    #pragma unroll
    for (int off = 2; off >= 1; off >>= 1) ss += __shfl_xor(ss, off, 4);
    const float sc = 1.0f / fmaxf(sqrtf(ss), EPSV);

    float* ck = ws + WS_CKN + ((size_t)sb*CC + cc)*DD + qd*16;
    float* cv = ws + WS_CV  + ((size_t)sb*CC + cc)*DD + qd*16;
    #pragma unroll
    for (int k = 0; k < 4; ++k) {
        float4 o = a[k]; o.x *= sc; o.y *= sc; o.z *= sc; o.w *= sc;
        *(float4*)&ck[k << 2] = o;
        *(float4*)&cv[k << 2] = *(const float4*)&vn[base + (k << 2)];
    }
}

// ---------------------------------------------------------------------------
// Kernel 3b: per (s,b,c) slot-softmax stats (max, sumexp) over M
// ---------------------------------------------------------------------------
__global__ __launch_bounds__(256)
void k3b_stats(const float* __restrict__ emK, const float* __restrict__ emS,
               const float* __restrict__ tau, const float* __restrict__ wwp,
               float* __restrict__ ws)
{
    const int sb = blockIdx.x; const int c = blockIdx.y;
    const int t = threadIdx.x;
    __shared__ float ck[64];
    __shared__ float z[MM];
    __shared__ float red[4];
    __shared__ float red2[4];

    if (t < 64) ck[t] = ws[WS_CKN + ((size_t)sb*CC + c)*DD + t];
    __syncthreads();
    const float invt = 1.0f / fmaxf(tau[sb], 0.01f);
    const float wwv = wwp[sb];
    const float* Kb = emK + (size_t)sb*MM*DD;
    const float* Sb = emS + (size_t)sb*MM;

    float lmax = -3.0e38f;
    for (int m = t; m < MM; m += 256) {
        float d = 0.f;
        #pragma unroll
        for (int ch = 0; ch < 16; ++ch) {
            const float4 k4 = *(const float4*)&Kb[(size_t)m*DD + (ch << 2)];
            const float4 c4 = *(const float4*)&ck[ch << 2];
            d += k4.x*c4.x + k4.y*c4.y + k4.z*c4.z + k4.w*c4.w;
        }
        const float zz = (d - wwv*Sb[m]) * invt;
        z[m] = zz;
        lmax = fmaxf(lmax, zz);
    }
    #pragma unroll
    for (int off = 32; off >= 1; off >>= 1) lmax = fmaxf(lmax, __shfl_xor(lmax, off, 64));
    if ((t & 63) == 0) red[t >> 6] = lmax;
    __syncthreads();
    const float bmax = fmaxf(fmaxf(red[0], red[1]), fmaxf(red[2], red[3]));

    float lsum = 0.f;
    for (int m = t; m < MM; m += 256) lsum += __expf(z[m] - bmax);
    #pragma unroll
    for (int off = 32; off >= 1; off >>= 1) lsum += __shfl_xor(lsum, off, 64);
    if ((t & 63) == 0) red2[t >> 6] = lsum;
    __syncthreads();
    if (t == 0) {
        ws[WS_MAXC + sb*CC + c] = bmax;
        ws[WS_SUMC + sb*CC + c] = red2[0] + red2[1] + red2[2] + red2[3];
    }
}

// ---------------------------------------------------------------------------
// Kernel 3c: per (s,b, 64-m tile): alpha, alpha_per_slot, blends, updates
// ---------------------------------------------------------------------------
__global__ __launch_bounds__(256)
void k3c_write(const float* __restrict__ emK, const float* __restrict__ emV,
               const float* __restrict__ emS, const float* __restrict__ emA,
               const float* __restrict__ gem, const float* __restrict__ tau,
               const float* __restrict__ dec, const float* __restrict__ wwp,
               float* __restrict__ outK, float* __restrict__ outV,
               float* __restrict__ outS, float* __restrict__ outA,
               float* __restrict__ ws)
{
    const int sb = blockIdx.x; const int m0 = blockIdx.y << 6;
    const int t = threadIdx.x;
    __shared__ float ckn[64][68];
    __shared__ float cvv[64][68];
    __shared__ float alphaT[64][64];   // [c][m]
    __shared__ float apsL[64];
    __shared__ float psum[4][64];
    __shared__ float pn[4][64];
    __shared__ float mx[64], gs[64], Sl[64];

    const float gv  = gem[sb];
    const float invt = 1.0f / fmaxf(tau[sb], 0.01f);
    const float wwv = wwp[sb];
    const float dcv = dec[sb];

    #pragma unroll
    for (int k = 0; k < 4; ++k) {
        const int fid = t + (k << 8);
        const int row = fid >> 4;
        const int col = (fid & 15) << 2;
        *(float4*)&ckn[row][col] = *(const float4*)&ws[WS_CKN + ((size_t)sb*CC + row)*DD + col];
        *(float4*)&cvv[row][col] = *(const float4*)&ws[WS_CV  + ((size_t)sb*CC + row)*DD + col];
    }
    if (t < 64) {
        const float cw = ws[WS_CW + sb*CC + t];
        mx[t] = ws[WS_MAXC + sb*CC + t];
        gs[t] = gv * cw / ws[WS_SUMC + sb*CC + t];
        Sl[t] = emS[(size_t)sb*MM + m0 + t];
    }
    __syncthreads();

    const int m = t & 63, w = t >> 6;

    // step 1: alphaT[c][m] for this wave's 16 c's
    {
        float acc[16];
        #pragma unroll
        for (int i = 0; i < 16; ++i) acc[i] = 0.f;
        const float* Krow = emK + ((size_t)sb*MM + m0 + m)*DD;
        #pragma unroll
        for (int ch = 0; ch < 16; ++ch) {
            const float4 k4 = *(const float4*)&Krow[ch << 2];
            #pragma unroll
            for (int i = 0; i < 16; ++i) {
                const float4 c4 = *(const float4*)&ckn[(w << 4) + i][ch << 2];
                acc[i] += k4.x*c4.x + k4.y*c4.y + k4.z*c4.z + k4.w*c4.w;
            }
        }
        const float Sv = Sl[m];
        #pragma unroll
        for (int i = 0; i < 16; ++i) {
            const int c = (w << 4) + i;
            const float zz = (acc[i] - wwv*Sv) * invt;
            alphaT[c][m] = gs[c] * __expf(zz - mx[c]);
        }
    }
    __syncthreads();

    // step 2: alpha_per_slot
    {
        float p = 0.f;
        #pragma unroll
        for (int i = 0; i < 16; ++i) p += alphaT[(w << 4) + i][m];
        psum[w][m] = p;
    }
    __syncthreads();
    if (t < 64) apsL[t] = (psum[0][t] + psum[1][t]) + (psum[2][t] + psum[3][t]);
    __syncthreads();

    // step 3: blends — this thread covers d in [w*16, w*16+16)
    float bk[16], bv[16];
    #pragma unroll
    for (int i = 0; i < 16; ++i) { bk[i] = 0.f; bv[i] = 0.f; }
    for (int cI = 0; cI < 64; ++cI) {
        const float a = alphaT[cI][m];
        #pragma unroll
        for (int k = 0; k < 4; ++k) {
            const float4 c4 = *(const float4*)&ckn[cI][(w << 4) + (k << 2)];
            const float4 v4 = *(const float4*)&cvv[cI][(w << 4) + (k << 2)];
            bk[(k<<2)+0] += a*c4.x; bk[(k<<2)+1] += a*c4.y;
            bk[(k<<2)+2] += a*c4.z; bk[(k<<2)+3] += a*c4.w;
            bv[(k<<2)+0] += a*v4.x; bv[(k<<2)+1] += a*v4.y;
            bv[(k<<2)+2] += a*v4.z; bv[(k<<2)+3] += a*v4.w;
        }
    }

    // step 4: normalize + update
    const float aps = apsL[m];
    const float idn = 1.0f / fmaxf(aps, EPSV);
    float ssq = 0.f;
    #pragma unroll
    for (int i = 0; i < 16; ++i) { bk[i] *= idn; bv[i] *= idn; ssq += bk[i]*bk[i]; }
    pn[w][m] = ssq;
    __syncthreads();
    const float nrm2 = (pn[0][m] + pn[1][m]) + (pn[2][m] + pn[3][m]);
    const float innv = 1.0f / fmaxf(sqrtf(nrm2), EPSV);
    const float ae = fminf(aps, 1.0f);
    const float oma = 1.0f - ae;
    const bool upd = aps > EPSV;
    const size_t gb = ((size_t)sb*MM + m0 + m)*DD + (w << 4);
    #pragma unroll
    for (int kq = 0; kq < 4; ++kq) {
        const float4 kk = *(const float4*)&emK[gb + (kq << 2)];
        const float4 vv = *(const float4*)&emV[gb + (kq << 2)];
        float4 nk, nv2;
        if (upd) {
            nk.x = oma*kk.x + ae*(bk[(kq<<2)+0]*innv);
            nk.y = oma*kk.y + ae*(bk[(kq<<2)+1]*innv);
            nk.z = oma*kk.z + ae*(bk[(kq<<2)+2]*innv);
            nk.w = oma*kk.w + ae*(bk[(kq<<2)+3]*innv);
            nv2.x = oma*vv.x + ae*bv[(kq<<2)+0];
            nv2.y = oma*vv.y + ae*bv[(kq<<2)+1];
            nv2.z = oma*vv.z + ae*bv[(kq<<2)+2];
            nv2.w = oma*vv.w + ae*bv[(kq<<2)+3];
        } else { nk = kk; nv2 = vv; }
        *(float4*)&outK[gb + (kq << 2)] = nk;
        *(float4*)&outV[gb + (kq << 2)] = nv2;
    }
    if (w == 0) {
        const float pre = fminf(fmaxf(Sl[m] + aps, 0.f), SMAXV) * dcv;
        outS[(size_t)sb*MM + m0 + m] = pre;
        outA[(size_t)sb*MM + m0 + m] = emA[(size_t)sb*MM + m0 + m] * (1.0f - aps);
        float tot = pre;
        #pragma unroll
        for (int off = 32; off >= 1; off >>= 1) tot += __shfl_xor(tot, off, 64);
        if (m == 0) atomicAdd(&ws[WS_TOTS + sb], tot);
    }
}

// ---------------------------------------------------------------------------
// Kernel 4: budget rescale of new_S
// ---------------------------------------------------------------------------
__global__ __launch_bounds__(256)
void k4_budget(float* __restrict__ outS, const float* __restrict__ ws)
{
    const int sb = blockIdx.x;
    const float sc = fminf(1.0f, BUDGETV / (ws[WS_TOTS + sb] + EPSV));
    for (int m = threadIdx.x; m < MM; m += 256)
        outS[(size_t)sb*MM + m] *= sc;
}

extern "C" void kernel_launch(void* const* d_in, const int* in_sizes, int n_in,
                              void* d_out, int out_size, void* d_ws, size_t ws_size,
                              hipStream_t stream)
{
    const float* q   = (const float*)d_in[0];
    const float* qnv = (const float*)d_in[1];
    const float* vnv = (const float*)d_in[2];
    const float* sur = (const float*)d_in[3];
    const float* wn  = (const float*)d_in[4];
    const float* gem = (const float*)d_in[5];
    const float* tau = (const float*)d_in[6];
    const float* dec = (const float*)d_in[7];
    const float* wwp = (const float*)d_in[8];
    const float* emK = (const float*)d_in[9];
    const float* emV = (const float*)d_in[10];
    const float* emS = (const float*)d_in[11];
    const float* emA = (const float*)d_in[12];

    float* out  = (float*)d_out;
    float* outK = out + 2097152;
    float* outV = out + 6291456;
    float* outS = out + 10485760;
    float* outA = out + 10551296;
    float* ws = (float*)d_ws;

    hipMemsetAsync((char*)d_ws + WS_TOTS*sizeof(float), 0, 32*sizeof(float), stream);

    k1_read<<<dim3(32, 64), 256, 0, stream>>>(q, qnv, sur, wn, emK, emV, emS, out, ws);
    k2_topc<<<32, 256, 0, stream>>>(ws);
    k3a_gather<<<32, 256, 0, stream>>>(qnv, vnv, ws);
    k3b_stats<<<dim3(32, 64), 256, 0, stream>>>(emK, emS, tau, wwp, ws);
    k3c_write<<<dim3(32, 32), 256, 0, stream>>>(emK, emV, emS, emA, gem, tau, dec, wwp,
                                                outK, outV, outS, outA, ws);
    k4_budget<<<32, 256, 0, stream>>>(outS, ws);
}

// Round 2
// 868.275 us; speedup vs baseline: 5.7980x; 5.7980x over previous
//
#include <hip/hip_runtime.h>
#include <math.h>

#define BSZ 4
#define NN 1024
#define BH 8
#define DD 64
#define MM 2048
#define KRET 16
#define CC 64
#define NEGV -1000000000.0f
#define EPSV 1e-8f
#define SMAXV 4.0f
#define BUDGETV 512.0f

// ws layout (float-element offsets)
#define WS_NOV  0         // [32][1024] novelty (transposed to [s*8+b][n])
#define WS_CI   32768     // int [32][64] candidate indices
#define WS_CW   34816     // [32][64] cand_weight
#define WS_CKN  36864     // [32][64][64] unit-normalized cand_K
#define WS_CV   167936    // [32][64][64] cand_V
#define WS_MAXC 299008    // [32][64] slot-softmax row max
#define WS_SUMC 301056    // [32][64] slot-softmax row sumexp
#define WS_TOTS 303104    // [32] new_S totals (memset to 0 each call)

// ---------------------------------------------------------------------------
// Kernel 1: scores = q.K^T with top-16 + softmax + P.V, sim = q_nov.K^T max,
// novelty output. One block = (s,b) x 16 rows of n. LDS-staged K tiles (64).
// R2: tile 128->64, acc 8->4, ch unroll 16->2, launch_bounds(256,2) to kill
// the R1 scratch spills (VGPR=256 + 6 GB scratch writes).
// ---------------------------------------------------------------------------
__global__ __launch_bounds__(256, 2)
void k1_read(const float* __restrict__ q, const float* __restrict__ qn,
             const float* __restrict__ surprise, const float* __restrict__ wnov,
             const float* __restrict__ emK, const float* __restrict__ emV,
             const float* __restrict__ emS, float* __restrict__ out,
             float* __restrict__ ws)
{
    const int sb = blockIdx.x;            // 0..31  (s*8+b) -> XCD locality
    const int s = sb >> 3, b = sb & 7;
    const int n0 = blockIdx.y << 4;       // n-tile of 16
    const int t = threadIdx.x;
    const int ir = t >> 4;                // row in tile 0..15
    const int c  = t & 15;                // sub-lane in row 0..15

    __shared__ float qs[16][68];
    __shared__ float qsn[16][68];
    __shared__ float Kt[64][68];
    __shared__ float Sm[64];
    __shared__ float win_e[16][16];
    __shared__ int   win_i[16][16];

    {
        const size_t qb = (((size_t)s*NN + n0 + ir)*BH + b)*DD + (c << 2);
        *(float4*)&qs[ir][c << 2]  = *(const float4*)&q[qb];
        *(float4*)&qsn[ir][c << 2] = *(const float4*)&qn[qb];
    }

    float tv[16]; int ti[16];
    #pragma unroll
    for (int i = 0; i < 16; ++i) { tv[i] = -3.0e38f; ti[i] = 0; }
    float minv = -3.0e38f; int minp = 0;
    float nsim = -3.0e38f;

    const float* Kb = emK + (size_t)sb*MM*DD;
    const float* Sb = emS + (size_t)sb*MM;

    #pragma unroll 1
    for (int mt = 0; mt < MM/64; ++mt) {
        __syncthreads();   // protect Kt from previous-iter readers
        #pragma unroll
        for (int k = 0; k < 4; ++k) {
            const int fid = t + (k << 8);
            const int row = fid >> 4;
            const int col = (fid & 15) << 2;
            *(float4*)&Kt[row][col] =
                *(const float4*)&Kb[((size_t)(mt*64 + row))*DD + col];
        }
        if (t < 64) Sm[t] = Sb[mt*64 + t];
        __syncthreads();

        float acc[4], accn[4];
        #pragma unroll
        for (int j = 0; j < 4; ++j) { acc[j] = 0.f; accn[j] = 0.f; }
        #pragma unroll 2
        for (int ch = 0; ch < 16; ++ch) {
            const float4 q4 = *(const float4*)&qs[ir][ch << 2];
            const float4 n4 = *(const float4*)&qsn[ir][ch << 2];
            #pragma unroll
            for (int j = 0; j < 4; ++j) {
                const float4 k4 = *(const float4*)&Kt[c + (j << 4)][ch << 2];
                acc[j]  += q4.x*k4.x + q4.y*k4.y + q4.z*k4.z + q4.w*k4.w;
                accn[j] += n4.x*k4.x + n4.y*k4.y + n4.z*k4.z + n4.w*k4.w;
            }
        }
        #pragma unroll
        for (int j = 0; j < 4; ++j) {
            const int ml = c + (j << 4);
            const bool act = Sm[ml] > 0.f;
            const float sq = act ? acc[j] : NEGV;
            nsim = fmaxf(nsim, act ? accn[j] : -1.0f);
            if (sq > minv) {
                const int gm = mt*64 + ml;
                #pragma unroll
                for (int i = 0; i < 16; ++i)
                    if (i == minp) { tv[i] = sq; ti[i] = gm; }
                minv = tv[0]; minp = 0;
                #pragma unroll
                for (int i = 1; i < 16; ++i)
                    if (tv[i] < minv) { minv = tv[i]; minp = i; }
            }
        }
    }

    // ---- merge per-row top-16 across the row's 16 lanes ----
    float m0 = 0.f;
    #pragma unroll 1
    for (int k = 0; k < 16; ++k) {
        float lv = tv[0]; int ls = 0;
        #pragma unroll
        for (int i = 1; i < 16; ++i) if (tv[i] > lv) { lv = tv[i]; ls = i; }
        int key = (c << 4) | ls;
        #pragma unroll
        for (int off = 8; off >= 1; off >>= 1) {
            const float ov = __shfl_xor(lv, off, 16);
            const int   ok = __shfl_xor(key, off, 16);
            if (ov > lv || (ov == lv && ok < key)) { lv = ov; key = ok; }
        }
        if (k == 0) m0 = lv;
        if ((key >> 4) == c) {
            const int sl = key & 15;
            int wi = 0;
            #pragma unroll
            for (int i = 0; i < 16; ++i) if (i == sl) wi = ti[i];
            win_e[ir][k] = __expf(lv - m0);
            win_i[ir][k] = wi;
            #pragma unroll
            for (int i = 0; i < 16; ++i) if (i == sl) tv[i] = -3.0e38f;
        }
    }
    __syncthreads();

    // ---- softmax over the 16 kept entries + P.V gather ----
    const float e_c = win_e[ir][c];
    const int   i_c = win_i[ir][c];
    float den = e_c;
    #pragma unroll
    for (int off = 8; off >= 1; off >>= 1) den += __shfl_xor(den, off, 16);
    const float wgt = e_c / den;

    float4 o4 = make_float4(0.f, 0.f, 0.f, 0.f);
    const float* Vb = emV + (size_t)sb*MM*DD;
    for (int k = 0; k < 16; ++k) {
        const float wk = __shfl(wgt, k, 16);
        const int   ik = __shfl(i_c, k, 16);
        const float4 v4 = *(const float4*)&Vb[(size_t)ik*DD + (c << 2)];
        o4.x += wk*v4.x; o4.y += wk*v4.y; o4.z += wk*v4.z; o4.w += wk*v4.w;
    }
    *(float4*)&out[(((size_t)s*NN + n0 + ir)*BH + b)*DD + (c << 2)] = o4;

    // ---- novelty ----
    #pragma unroll
    for (int off = 8; off >= 1; off >>= 1)
        nsim = fmaxf(nsim, __shfl_xor(nsim, off, 16));
    if (c == 0) {
        const int ni = ((s*NN + n0 + ir)*BH) + b;
        const float w = wnov[ni], su = surprise[ni];
        ws[WS_NOV + sb*NN + n0 + ir] = w*su + (1.f - w)*(1.f - fmaxf(nsim, 0.f));
    }
}

// ---------------------------------------------------------------------------
// Kernel 2: per (s,b) top-64 of novelty over N=1024 + cand_weight
// ---------------------------------------------------------------------------
__global__ __launch_bounds__(256)
void k2_topc(float* __restrict__ ws)
{
    const int sb = blockIdx.x;
    const int t = threadIdx.x;
    __shared__ float nv[NN];
    __shared__ float rv[4]; __shared__ int ri[4];
    __shared__ float kvv[CC]; __shared__ int kii[CC];

    #pragma unroll
    for (int k = 0; k < 4; ++k) nv[t + (k << 8)] = ws[WS_NOV + sb*NN + t + (k << 8)];
    __syncthreads();
    const int lane = t & 63, w = t >> 6;

    for (int k = 0; k < CC; ++k) {
        float lv = -3.0e38f; int li = 0;
        #pragma unroll
        for (int j = 0; j < 4; ++j) {
            const int idx = t + (j << 8);
            const float v = nv[idx];
            if (v > lv) { lv = v; li = idx; }
        }
        #pragma unroll
        for (int off = 32; off >= 1; off >>= 1) {
            const float ov = __shfl_xor(lv, off, 64);
            const int   oi = __shfl_xor(li, off, 64);
            if (ov > lv || (ov == lv && oi < li)) { lv = ov; li = oi; }
        }
        if (lane == 0) { rv[w] = lv; ri[w] = li; }
        __syncthreads();
        if (t == 0) {
            float bv2 = rv[0]; int bi = ri[0];
            for (int j = 1; j < 4; ++j)
                if (rv[j] > bv2 || (rv[j] == bv2 && ri[j] < bi)) { bv2 = rv[j]; bi = ri[j]; }
            kvv[k] = bv2; kii[k] = bi;
            nv[bi] = -3.0e38f;
        }
        __syncthreads();
    }

    if (t < CC) {
        const float v = kvv[t];
        float sum = v;
        #pragma unroll
        for (int off = 32; off >= 1; off >>= 1) sum += __shfl_xor(sum, off, 64);
        ((int*)ws)[WS_CI + sb*CC + t] = kii[t];
        ws[WS_CW + sb*CC + t] = v / (sum + EPSV);
    }
}

// ---------------------------------------------------------------------------
// Kernel 3a: gather cand_K/cand_V, unit-normalize cand_K
// ---------------------------------------------------------------------------
__global__ __launch_bounds__(256)
void k3a_gather(const float* __restrict__ qn, const float* __restrict__ vn,
                float* __restrict__ ws)
{
    const int sb = blockIdx.x; const int s = sb >> 3, b = sb & 7;
    const int t = threadIdx.x;
    const int cc = t >> 2, qd = t & 3;
    const int idx = ((const int*)ws)[WS_CI + sb*CC + cc];
    const size_t base = (((size_t)s*NN + idx)*BH + b)*DD + qd*16;

    float4 a[4]; float ss = 0.f;
    #pragma unroll
    for (int k = 0; k < 4; ++k) {
        a[k] = *(const float4*)&qn[base + (k << 2)];
        ss += a[k].x*a[k].x + a[k].y*a[k].y + a[k].z*a[k].z + a[k].w*a[k].w;
    }
    #pragma unroll
    for (int off = 2; off >= 1; off >>= 1) ss += __shfl_xor(ss, off, 4);
    const float sc = 1.0f / fmaxf(sqrtf(ss), EPSV);

    float* ck = ws + WS_CKN + ((size_t)sb*CC + cc)*DD + qd*16;
    float* cv = ws + WS_CV  + ((size_t)sb*CC + cc)*DD + qd*16;
    #pragma unroll
    for (int k = 0; k < 4; ++k) {
        float4 o = a[k]; o.x *= sc; o.y *= sc; o.z *= sc; o.w *= sc;
        *(float4*)&ck[k << 2] = o;
        *(float4*)&cv[k << 2] = *(const float4*)&vn[base + (k << 2)];
    }
}

// ---------------------------------------------------------------------------
// Kernel 3b: per (s,b,c) slot-softmax stats (max, sumexp) over M
// ---------------------------------------------------------------------------
__global__ __launch_bounds__(256)
void k3b_stats(const float* __restrict__ emK, const float* __restrict__ emS,
               const float* __restrict__ tau, const float* __restrict__ wwp,
               float* __restrict__ ws)
{
    const int sb = blockIdx.x; const int c = blockIdx.y;
    const int t = threadIdx.x;
    __shared__ float ck[64];
    __shared__ float z[MM];
    __shared__ float red[4];
    __shared__ float red2[4];

    if (t < 64) ck[t] = ws[WS_CKN + ((size_t)sb*CC + c)*DD + t];
    __syncthreads();
    const float invt = 1.0f / fmaxf(tau[sb], 0.01f);
    const float wwv = wwp[sb];
    const float* Kb = emK + (size_t)sb*MM*DD;
    const float* Sb = emS + (size_t)sb*MM;

    float lmax = -3.0e38f;
    for (int m = t; m < MM; m += 256) {
        float d = 0.f;
        #pragma unroll
        for (int ch = 0; ch < 16; ++ch) {
            const float4 k4 = *(const float4*)&Kb[(size_t)m*DD + (ch << 2)];
            const float4 c4 = *(const float4*)&ck[ch << 2];
            d += k4.x*c4.x + k4.y*c4.y + k4.z*c4.z + k4.w*c4.w;
        }
        const float zz = (d - wwv*Sb[m]) * invt;
        z[m] = zz;
        lmax = fmaxf(lmax, zz);
    }
    #pragma unroll
    for (int off = 32; off >= 1; off >>= 1) lmax = fmaxf(lmax, __shfl_xor(lmax, off, 64));
    if ((t & 63) == 0) red[t >> 6] = lmax;
    __syncthreads();
    const float bmax = fmaxf(fmaxf(red[0], red[1]), fmaxf(red[2], red[3]));

    float lsum = 0.f;
    for (int m = t; m < MM; m += 256) lsum += __expf(z[m] - bmax);
    #pragma unroll
    for (int off = 32; off >= 1; off >>= 1) lsum += __shfl_xor(lsum, off, 64);
    if ((t & 63) == 0) red2[t >> 6] = lsum;
    __syncthreads();
    if (t == 0) {
        ws[WS_MAXC + sb*CC + c] = bmax;
        ws[WS_SUMC + sb*CC + c] = red2[0] + red2[1] + red2[2] + red2[3];
    }
}

// ---------------------------------------------------------------------------
// Kernel 3c: per (s,b, 64-m tile): alpha, alpha_per_slot, blends, updates
// ---------------------------------------------------------------------------
__global__ __launch_bounds__(256)
void k3c_write(const float* __restrict__ emK, const float* __restrict__ emV,
               const float* __restrict__ emS, const float* __restrict__ emA,
               const float* __restrict__ gem, const float* __restrict__ tau,
               const float* __restrict__ dec, const float* __restrict__ wwp,
             float* __restrict__ outK, float* __restrict__ outV,
             float* __restrict__ outS, float* __restrict__ outA,
             float* __restrict__ ws)
{
    const int sb = blockIdx.x; const int m0 = blockIdx.y << 6;
    const int t = threadIdx.x;
    __shared__ float ckn[64][68];
    __shared__ float cvv[64][68];
    __shared__ float alphaT[64][64];   // [c][m]
    __shared__ float apsL[64];
    __shared__ float psum[4][64];
    __shared__ float pn[4][64];
    __shared__ float mx[64], gs[64], Sl[64];

    const float gv  = gem[sb];
    const float invt = 1.0f / fmaxf(tau[sb], 0.01f);
    const float wwv = wwp[sb];
    const float dcv = dec[sb];

    #pragma unroll
    for (int k = 0; k < 4; ++k) {
        const int fid = t + (k << 8);
        const int row = fid >> 4;
        const int col = (fid & 15) << 2;
        *(float4*)&ckn[row][col] = *(const float4*)&ws[WS_CKN + ((size_t)sb*CC + row)*DD + col];
        *(float4*)&cvv[row][col] = *(const float4*)&ws[WS_CV  + ((size_t)sb*CC + row)*DD + col];
    }
    if (t < 64) {
        const float cw = ws[WS_CW + sb*CC + t];
        mx[t] = ws[WS_MAXC + sb*CC + t];
        gs[t] = gv * cw / ws[WS_SUMC + sb*CC + t];
        Sl[t] = emS[(size_t)sb*MM + m0 + t];
    }
    __syncthreads();

    const int m = t & 63, w = t >> 6;

    // step 1: alphaT[c][m] for this wave's 16 c's
    {
        float acc[16];
        #pragma unroll
        for (int i = 0; i < 16; ++i) acc[i] = 0.f;
        const float* Krow = emK + ((size_t)sb*MM + m0 + m)*DD;
        #pragma unroll 4
        for (int ch = 0; ch < 16; ++ch) {
            const float4 k4 = *(const float4*)&Krow[ch << 2];
            #pragma unroll
            for (int i = 0; i < 16; ++i) {
                const float4 c4 = *(const float4*)&ckn[(w << 4) + i][ch << 2];
                acc[i] += k4.x*c4.x + k4.y*c4.y + k4.z*c4.z + k4.w*c4.w;
            }
        }
        const float Sv = Sl[m];
        #pragma unroll
        for (int i = 0; i < 16; ++i) {
            const int c = (w << 4) + i;
            const float zz = (acc[i] - wwv*Sv) * invt;
            alphaT[c][m] = gs[c] * __expf(zz - mx[c]);
        }
    }
    __syncthreads();

    // step 2: alpha_per_slot
    {
        float p = 0.f;
        #pragma unroll
        for (int i = 0; i < 16; ++i) p += alphaT[(w << 4) + i][m];
        psum[w][m] = p;
    }
    __syncthreads();
    if (t < 64) apsL[t] = (psum[0][t] + psum[1][t]) + (psum[2][t] + psum[3][t]);
    __syncthreads();

    // step 3: blends — this thread covers d in [w*16, w*16+16)
    float bk[16], bv[16];
    #pragma unroll
    for (int i = 0; i < 16; ++i) { bk[i] = 0.f; bv[i] = 0.f; }
    for (int cI = 0; cI < 64; ++cI) {
        const float a = alphaT[cI][m];
        #pragma unroll
        for (int k = 0; k < 4; ++k) {
            const float4 c4 = *(const float4*)&ckn[cI][(w << 4) + (k << 2)];
            const float4 v4 = *(const float4*)&cvv[cI][(w << 4) + (k << 2)];
            bk[(k<<2)+0] += a*c4.x; bk[(k<<2)+1] += a*c4.y;
            bk[(k<<2)+2] += a*c4.z; bk[(k<<2)+3] += a*c4.w;
            bv[(k<<2)+0] += a*v4.x; bv[(k<<2)+1] += a*v4.y;
            bv[(k<<2)+2] += a*v4.z; bv[(k<<2)+3] += a*v4.w;
        }
    }

    // step 4: normalize + update
    const float aps = apsL[m];
    const float idn = 1.0f / fmaxf(aps, EPSV);
    float ssq = 0.f;
    #pragma unroll
    for (int i = 0; i < 16; ++i) { bk[i] *= idn; bv[i] *= idn; ssq += bk[i]*bk[i]; }
    pn[w][m] = ssq;
    __syncthreads();
    const float nrm2 = (pn[0][m] + pn[1][m]) + (pn[2][m] + pn[3][m]);
    const float innv = 1.0f / fmaxf(sqrtf(nrm2), EPSV);
    const float ae = fminf(aps, 1.0f);
    const float oma = 1.0f - ae;
    const bool upd = aps > EPSV;
    const size_t gb = ((size_t)sb*MM + m0 + m)*DD + (w << 4);
    #pragma unroll
    for (int kq = 0; kq < 4; ++kq) {
        const float4 kk = *(const float4*)&emK[gb + (kq << 2)];
        const float4 vv = *(const float4*)&emV[gb + (kq << 2)];
        float4 nk, nv2;
        if (upd) {
            nk.x = oma*kk.x + ae*(bk[(kq<<2)+0]*innv);
            nk.y = oma*kk.y + ae*(bk[(kq<<2)+1]*innv);
            nk.z = oma*kk.z + ae*(bk[(kq<<2)+2]*innv);
            nk.w = oma*kk.w + ae*(bk[(kq<<2)+3]*innv);
            nv2.x = oma*vv.x + ae*bv[(kq<<2)+0];
            nv2.y = oma*vv.y + ae*bv[(kq<<2)+1];
            nv2.z = oma*vv.z + ae*bv[(kq<<2)+2];
            nv2.w = oma*vv.w + ae*bv[(kq<<2)+3];
        } else { nk = kk; nv2 = vv; }
        *(float4*)&outK[gb + (kq << 2)] = nk;
        *(float4*)&outV[gb + (kq << 2)] = nv2;
    }
    if (w == 0) {
        const float pre = fminf(fmaxf(Sl[m] + aps, 0.f), SMAXV) * dcv;
        outS[(size_t)sb*MM + m0 + m] = pre;
        outA[(size_t)sb*MM + m0 + m] = emA[(size_t)sb*MM + m0 + m] * (1.0f - aps);
        float tot = pre;
        #pragma unroll
        for (int off = 32; off >= 1; off >>= 1) tot += __shfl_xor(tot, off, 64);
        if (m == 0) atomicAdd(&ws[WS_TOTS + sb], tot);
    }
}

// ---------------------------------------------------------------------------
// Kernel 4: budget rescale of new_S
// ---------------------------------------------------------------------------
__global__ __launch_bounds__(256)
void k4_budget(float* __restrict__ outS, const float* __restrict__ ws)
{
    const int sb = blockIdx.x;
    const float sc = fminf(1.0f, BUDGETV / (ws[WS_TOTS + sb] + EPSV));
    for (int m = threadIdx.x; m < MM; m += 256)
        outS[(size_t)sb*MM + m] *= sc;
}

extern "C" void kernel_launch(void* const* d_in, const int* in_sizes, int n_in,
                              void* d_out, int out_size, void* d_ws, size_t ws_size,
                              hipStream_t stream)
{
    const float* q   = (const float*)d_in[0];
    const float* qnv = (const float*)d_in[1];
    const float* vnv = (const float*)d_in[2];
    const float* sur = (const float*)d_in[3];
    const float* wn  = (const float*)d_in[4];
    const float* gem = (const float*)d_in[5];
    const float* tau = (const float*)d_in[6];
    const float* dec = (const float*)d_in[7];
    const float* wwp = (const float*)d_in[8];
    const float* emK = (const float*)d_in[9];
    const float* emV = (const float*)d_in[10];
    const float* emS = (const float*)d_in[11];
    const float* emA = (const float*)d_in[12];

    float* out  = (float*)d_out;
    float* outK = out + 2097152;
    float* outV = out + 6291456;
    float* outS = out + 10485760;
    float* outA = out + 10551296;
    float* ws = (float*)d_ws;

    hipMemsetAsync((char*)d_ws + WS_TOTS*sizeof(float), 0, 32*sizeof(float), stream);

    k1_read<<<dim3(32, 64), 256, 0, stream>>>(q, qnv, sur, wn, emK, emV, emS, out, ws);
    k2_topc<<<32, 256, 0, stream>>>(ws);
    k3a_gather<<<32, 256, 0, stream>>>(qnv, vnv, ws);
    k3b_stats<<<dim3(32, 64), 256, 0, stream>>>(emK, emS, tau, wwp, ws);
    k3c_write<<<dim3(32, 32), 256, 0, stream>>>(emK, emV, emS, emA, gem, tau, dec, wwp,
                                                outK, outV, outS, outA, ws);
    k4_budget<<<32, 256, 0, stream>>>(outS, ws);
}